// Round 12
// baseline (38203.909 us; speedup 1.0000x reference)
//
#include <hip/hip_runtime.h>
#include <hip/hip_bf16.h>
#include <hip/hip_fp16.h>
#include <math.h>

#define CS 96      // source len
#define CT 96      // target len
#define CE 256     // embed
#define CH 512     // hidden
#define CH2 1024
#define CH3 1536
#define CV 32000
#define CXD 1280   // E + 2H

typedef unsigned int u32;
typedef unsigned short u16;
typedef unsigned long long u64;

__device__ __forceinline__ float sigm(float x){ return 1.f/(1.f+expf(-x)); }

// packed-fp16 dot2 with fp32 accumulate
__device__ __forceinline__ float dot2f(u32 a, u32 b, float c){
#if __has_builtin(__builtin_amdgcn_fdot2)
  typedef _Float16 hv2 __attribute__((ext_vector_type(2)));
  hv2 x = __builtin_bit_cast(hv2, a), y = __builtin_bit_cast(hv2, b);
  return __builtin_amdgcn_fdot2(x, y, c, false);
#else
  __half2 x = __builtin_bit_cast(__half2, a), y = __builtin_bit_cast(__half2, b);
  return c + __half2float(x.x)*__half2float(y.x) + __half2float(x.y)*__half2float(y.y);
#endif
}

// i8x4 dot with i32 accumulate
__device__ __forceinline__ int sdot4(u32 a, u32 b, int c){
#if __has_builtin(__builtin_amdgcn_sdot4)
  return __builtin_amdgcn_sdot4(a, b, c, false);
#else
  int r = c;
  #pragma unroll
  for (int i=0;i<4;i++){
    int xa = (int)((a >> (8*i)) & 255u); xa = (xa ^ 128) - 128;
    int xb = (int)((b >> (8*i)) & 255u); xb = (xb ^ 128) - 128;
    r += xa*xb;
  }
  return r;
#endif
}

__device__ __forceinline__ u32 packh2(float a, float b){
  return (u32)__half_as_ushort(__float2half(a)) | ((u32)__half_as_ushort(__float2half(b)) << 16);
}

// lgkm-only barrier: drains LDS ops, NOT global stores
#define COVBAR() do{ asm volatile("s_waitcnt lgkmcnt(0)" ::: "memory"); \
                     __builtin_amdgcn_sched_barrier(0); \
                     __builtin_amdgcn_s_barrier(); \
                     __builtin_amdgcn_sched_barrier(0); }while(0)

// ---------------- init: cov_last ----------------
__global__ void k_init(float* cov_last){
  int i = threadIdx.x;
  for (int j = i; j < CH; j += 256) cov_last[j] = 0.f;
}

// ---------------- embedding gathers ----------------
__global__ void k_embed(const int* iseq, const int* oseq, const float* ee, const float* de,
                        float* x_enc, float* x_dec){
  int s = blockIdx.x, d = threadIdx.x;
  x_enc[s*CE+d] = ee[(long)iseq[s]*CE + d];
  x_dec[s*CE+d] = de[(long)oseq[s]*CE + d];
}

// ---------------- encoder input-gate precompute ----------------
__global__ void k_gi(const float* Wf, const float* bf, const float* Wb, const float* bb,
                     const float* x_enc, float* gf, float* gb){
  int idx = blockIdx.x*256 + threadIdx.x;
  int dir = idx / (CS*CH3);
  int rem = idx - dir*(CS*CH3);
  int s = rem / CH3, r = rem - s*CH3;
  const float* W = dir ? Wb : Wf;
  const float* b = dir ? bb : bf;
  const float* x = x_enc + s*CE;
  const float* w = W + (long)r*CE;
  float acc = b[r];
  #pragma unroll 8
  for (int k=0;k<CE;k++) acc += w[k]*x[k];
  (dir ? gb : gf)[s*CH3 + r] = acc;
}

// ---------------- one encoder step ----------------
__global__ void k_enc_step(int s, const float* Whf, const float* bhf, const float* Whb, const float* bhb,
                           const float* gf, const float* gb, float* outf, float* outb){
  int wg = blockIdx.x;
  int dir = wg >> 3;
  int jb = (wg & 7)*64;
  int t = threadIdx.x;
  int j = jb + (t>>2);
  int c0 = (t&3)*128;
  const float* Whh = dir ? Whb : Whf;
  const float* bhh = dir ? bhb : bhf;
  const float* gi  = dir ? gb : gf;
  float* o = dir ? outb : outf;
  int pos = dir ? (CS-1-s) : s;
  const float* hp = (s>0) ? (o + (dir ? (pos+1)*CH : (s-1)*CH)) : nullptr;
  float ar=0.f, az=0.f, an=0.f;
  if (s > 0){
    const float* wr = Whh + (long)j*CH;
    const float* wz = Whh + (long)(j+CH)*CH;
    const float* wn = Whh + (long)(j+2*CH)*CH;
    #pragma unroll 4
    for (int k=c0;k<c0+128;k++){
      float h = hp[k];
      ar += wr[k]*h; az += wz[k]*h; an += wn[k]*h;
    }
  }
  ar += __shfl_xor(ar,1); ar += __shfl_xor(ar,2);
  az += __shfl_xor(az,1); az += __shfl_xor(az,2);
  an += __shfl_xor(an,1); an += __shfl_xor(an,2);
  if ((t&3)==0){
    const float* g = gi + pos*CH3;
    float hpj = (s>0) ? hp[j] : 0.f;
    float r = sigm(g[j]       + ar + bhh[j]);
    float z = sigm(g[j+CH]    + az + bhh[j+CH]);
    float n = tanhf(g[j+2*CH] + r*(an + bhh[j+2*CH]));
    o[pos*CH + j] = (1.f-z)*n + z*hpj;
  }
}

// ---------------- ua_enc / Aenc precompute + h_carry init ----------------
__global__ void k_prep2(const float* ua, const float* Wic, const float* outf, const float* outb,
                        float* ua_enc, float* Aenc, float* h_carry){
  int idx = blockIdx.x*256 + threadIdx.x;
  if (idx < 2*CS*CH){
    int which = idx / (CS*CH);
    int rem = idx - which*(CS*CH);
    int s = rem / CH, r = rem - s*CH;
    const float* of = outf + s*CH;
    const float* ob = outb + s*CH;
    const float* w = which ? (Wic + (long)r*CH3) : (ua + (long)r*CH2);
    float acc = 0.f;
    #pragma unroll 4
    for (int k=0;k<CH;k++) acc += w[k]*of[k];
    #pragma unroll 4
    for (int k=0;k<CH;k++) acc += w[CH+k]*ob[k];
    (which ? Aenc : ua_enc)[s*CH + r] = acc;
  } else if (idx < 2*CS*CH + CH){
    int j = idx - 2*CS*CH;
    h_carry[j] = outf[(CS-1)*CH + j];
  }
}

// ---------------- fp32 -> bf16 (RNE) for lin_W ----------------
__global__ void k_cvt(const float* w, u16* o, int n){
  int i = blockIdx.x*blockDim.x + threadIdx.x;
  int stride = gridDim.x*blockDim.x;
  for (; i<n; i+=stride){
    union { float f; u32 u; } v; v.f = w[i];
    u32 r = (v.u + 0x7fffu + ((v.u>>16)&1u)) >> 16;
    o[i] = (u16)r;
  }
}

// ---------------- fp32 -> fp16 for Wih_c[:,1024:1536] ----------------
__global__ void k_cvt_cov(const float* Wic, u16* wic16){
  int i = blockIdx.x*256 + threadIdx.x;     // CH*CH total
  int r = i >> 9, c = i & 511;
  wic16[i] = __half_as_ushort(__float2half(Wic[(size_t)r*CH3 + CH2 + c]));
}

// ---------------- Whh_c -> i8 (per-row scale) ----------------
__global__ void k_quant(const float* Whc, u32* w8, float* rs){
  int r = blockIdx.x;          // 512 blocks x 64 threads
  int l = threadIdx.x;
  const float* wr = Whc + (size_t)r*CH;
  float m = 0.f;
  for (int k=l; k<CH; k+=64) m = fmaxf(m, fabsf(wr[k]));
  for (int d=1; d<64; d<<=1) m = fmaxf(m, __shfl_xor(m,d));
  float sc = (m > 0.f) ? (127.f/m) : 0.f;
  for (int wi=l; wi<128; wi+=64){
    u32 p = 0;
    #pragma unroll
    for (int j=0;j<4;j++){
      int q = (int)rintf(wr[wi*4+j]*sc);
      q = max(-127, min(127, q));
      p |= (u32)(q & 255) << (8*j);
    }
    w8[(size_t)r*128 + wi] = p;
  }
  if (l==0) rs[r] = m/(127.f*127.f);
}

// ---------------- wah = wa @ h (pre-loop only) ----------------
__global__ void k_wah(const float* wa, const float* h, float* wah){
  int j = blockIdx.x*64 + (threadIdx.x>>2);
  int c0 = (threadIdx.x&3)*128;
  const float* w = wa + (long)j*CH;
  float acc = 0.f;
  #pragma unroll 4
  for (int k=c0;k<c0+128;k++) acc += w[k]*h[k];
  acc += __shfl_xor(acc,1); acc += __shfl_xor(acc,2);
  if ((threadIdx.x&3)==0) wah[j] = acc;
}

// ---------------- attention scores e[s] ----------------
__global__ void k_attn(int t, const float* vc, const float* va,
                       const float* ua_enc, const float* cov_vec, const float* wah, float* e){
  int s = blockIdx.x, tid = threadIdx.x;
  __shared__ float red[4];
  float sum = 0.f;
  #pragma unroll
  for (int jj=0;jj<2;jj++){
    int j = tid + jj*256;
    float acc = ua_enc[s*CH + j] + wah[j];
    if (t > 0){
      const float* v = vc + (long)j*CH;
      const float* cvs = cov_vec + s*CH;
      #pragma unroll 4
      for (int k=0;k<CH;k++) acc += v[k]*cvs[k];
    }
    sum += va[j]*tanhf(acc);
  }
  for (int m=1;m<64;m<<=1) sum += __shfl_xor(sum,m);
  if ((tid&63)==0) red[tid>>6] = sum;
  __syncthreads();
  if (tid==0) e[s] = red[0]+red[1]+red[2]+red[3];
}

// ---------------- softmax + context ----------------
__global__ void k_soft(const float* e, const float* outf, const float* outb, float* alpha, float* ctx){
  int tid = threadIdx.x; // 128
  __shared__ float al[CS];
  __shared__ float rmax[2], rsum[2];
  float v = (tid<CS) ? e[tid] : -1e30f;
  float m = v;
  for (int k=1;k<64;k<<=1) m = fmaxf(m, __shfl_xor(m,k));
  if ((tid&63)==0) rmax[tid>>6] = m;
  __syncthreads();
  float gm = fmaxf(rmax[0], rmax[1]);
  float ex = (tid<CS) ? expf(v-gm) : 0.f;
  float sm2 = ex;
  for (int k=1;k<64;k<<=1) sm2 += __shfl_xor(sm2,k);
  if ((tid&63)==0) rsum[tid>>6] = sm2;
  __syncthreads();
  float inv = 1.f/(rsum[0]+rsum[1]);
  if (tid<CS){ float a = ex*inv; al[tid] = a; alpha[tid] = a; }
  __syncthreads();
  #pragma unroll
  for (int k=0;k<8;k++){
    int d = k*128 + tid;
    const float* src = (d<CH) ? outf : outb;
    int dd = (d<CH) ? d : d-CH;
    float acc = 0.f;
    for (int s2=0;s2<CS;s2++) acc += al[s2]*src[s2*CH+dd];
    ctx[d] = acc;
  }
}

// ---------------- decoder GRU ----------------
__global__ void k_gru(int t, const float* Wi, const float* bi, const float* Wh, const float* bh,
                      const float* ctx, const float* x_dec, const float* h_carry, float* h_cur){
  int wg = blockIdx.x, tid = threadIdx.x;
  int j = wg*8 + (tid>>5);
  int ln = tid&31;
  const float* xd = x_dec + t*CE;
  float ar=0.f, az=0.f, an=0.f;
  {
    int c0 = ln*40;
    const float* wr = Wi + (long)j*CXD;
    const float* wz = Wi + (long)(j+CH)*CXD;
    const float* wn = Wi + (long)(j+2*CH)*CXD;
    for (int k=c0;k<c0+40;k++){
      float x = (k<CH2) ? ctx[k] : xd[k-CH2];
      ar += wr[k]*x; az += wz[k]*x; an += wn[k]*x;
    }
  }
  float hr=0.f, hz=0.f, hn2=0.f;
  {
    int c0 = ln*16;
    const float* wr = Wh + (long)j*CH;
    const float* wz = Wh + (long)(j+CH)*CH;
    const float* wn = Wh + (long)(j+2*CH)*CH;
    for (int k=c0;k<c0+16;k++){
      float hv = h_carry[k];
      hr += wr[k]*hv; hz += wz[k]*hv; hn2 += wn[k]*hv;
    }
  }
  for (int m=1;m<32;m<<=1){
    ar+=__shfl_xor(ar,m); az+=__shfl_xor(az,m); an+=__shfl_xor(an,m);
    hr+=__shfl_xor(hr,m); hz+=__shfl_xor(hz,m); hn2+=__shfl_xor(hn2,m);
  }
  if (ln==0){
    float hprev = h_carry[j];
    float r = sigm(ar + bi[j]       + hr + bh[j]);
    float z = sigm(az + bi[j+CH]    + hz + bh[j+CH]);
    float n = tanhf(an + bi[j+2*CH] + r*(hn2 + bh[j+2*CH]));
    h_cur[j] = (1.f-z)*n + z*hprev;
  }
}

// ---------------- fused tail: block 0 cov SOLO | 1,2 wah | 3..52 logits ----------------
// coverage: ONE workgroup, i8 weights fully in VGPRs (64 u32/thread x 1024 threads = 256 KB),
// h as i8 held 1 word/lane per wave; dot via v_readlane + v_dot4_i32_i8.  No cross-WG sync.
template<int BF16>
__launch_bounds__(1024, 4)
__global__ void k_tail(int t, const void* Wv, const float* lb, const float* h_cur, const float* ctx,
                       float* out, const float* wa, float* wah,
                       const u32* w8, const float* rs, const u16* wic16,
                       const float* bic, const float* bhc,
                       const float* Aenc, const float* alpha,
                       float* cov_vec, float* cov_last, float* h_carry){
  int b = blockIdx.x, tid = threadIdx.x;

  if (b >= 3){
    // ---- logits: 50 blocks x 16 waves = 800 row-walkers ----
    int ln = tid&63;
    int gw = (b-3)*16 + (tid>>6);   // 0..799
    float x[24];
    #pragma unroll
    for (int k=0;k<24;k++){
      int c = k*64 + ln;
      x[k] = (c<CH) ? h_cur[c] : ctx[c-CH];
    }
    for (int r=gw; r<CV; r+=800){
      float acc = 0.f;
      if (BF16){
        const u16* w = (const u16*)Wv + (long)r*CH3;
        #pragma unroll
        for (int k=0;k<24;k++){
          u32 u = (u32)w[k*64+ln] << 16;
          acc += __uint_as_float(u)*x[k];
        }
      } else {
        const float* w = (const float*)Wv + (long)r*CH3;
        #pragma unroll
        for (int k=0;k<24;k++) acc += w[k*64+ln]*x[k];
      }
      for (int m=1;m<64;m<<=1) acc += __shfl_xor(acc,m);
      if (ln==0) out[(long)t*CV + r] = acc + lb[r];
    }
    return;
  }

  if (b >= 1){
    // ---- wah = wa @ h_cur for next step (skip at t=0: keeps wa@h_enc) ----
    if (t > 0){
      int j = (b-1)*256 + (tid>>2);
      int cq = (tid&3)*128;
      const float* w = wa + (long)j*CH;
      float acc = 0.f;
      #pragma unroll 4
      for (int k=cq;k<cq+128;k++) acc += w[k]*h_cur[k];
      acc += __shfl_xor(acc,1); acc += __shfl_xor(acc,2);
      if ((tid&3)==0) wah[j] = acc;
    }
    return;
  }

  // ================= coverage solo (1024 threads, ONE CU, no cross-WG sync) =================
  const float* h_dec = (t==0) ? h_carry : h_cur;
  int half = tid >> 9;       // 0: cols 0..255, 1: cols 256..511
  int row  = tid & 511;
  int lane = tid & 63;

  __shared__ u32 part_l[1024];     // i32 partials (also reused for bacc f32 partials)
  __shared__ u32 h8[128];          // h as i8x4 (512 bytes)
  __shared__ u32 hd16[256];        // h_dec fp16 pairs (for bacc)
  __shared__ float al_l[CS];

  if (tid < CS) al_l[tid] = alpha[tid];
  if (tid < 256) hd16[tid] = packh2(h_dec[2*tid], h_dec[2*tid+1]);
  __syncthreads();   // hd16 + al ready

  // ---- bacc partials: thread = (row rw = tid>>1, seg = tid&1 of 256 cols), fp16 dot ----
  {
    int rw = tid >> 1, sg = tid & 1;
    const uint4* bw = (const uint4*)(wic16 + (size_t)rw*CH + sg*256);
    float bp = 0.f;
    #pragma unroll
    for (int k=0;k<32;k++){
      uint4 wv = bw[k];
      const uint4 hv = *(const uint4*)&hd16[sg*128 + 4*k];
      bp = dot2f(wv.x,hv.x,bp); bp = dot2f(wv.y,hv.y,bp);
      bp = dot2f(wv.z,hv.z,bp); bp = dot2f(wv.w,hv.w,bp);
      if ((k&3)==3) asm volatile("" ::: "memory");   // cap in-flight loads
    }
    part_l[tid] = __float_as_uint(bp);
  }

  // ---- i8 weights -> 64 VGPRs: w8[row][half*64 + k] ----
  u32 wreg[64];
  {
    const u32* wp = w8 + (size_t)row*128 + half*64;
    #pragma unroll
    for (int k=0;k<64;k+=4){
      uint4 v = *(const uint4*)(wp + k);
      wreg[k]=v.x; wreg[k+1]=v.y; wreg[k+2]=v.z; wreg[k+3]=v.w;
      if ((k&15)==12) asm volatile("" ::: "memory");
    }
  }
  __syncthreads();   // bacc partials ready

  float bacc_r=0.f, bsum_r=0.f, rs_r=0.f, a_next=0.f;
  if (tid < 512){
    bacc_r = __uint_as_float(part_l[2*tid]) + __uint_as_float(part_l[2*tid+1]);
    bsum_r = bic[tid] + bhc[tid];
    rs_r = rs[tid];
    a_next = Aenc[tid];
    cov_vec[tid] = tanhf(cov_last[tid]);   // cov_vec position-0 entry
    if (t > 0) h_carry[tid] = h_dec[tid];  // commit carry
  }
  __syncthreads();   // part_l free for reuse

  for (int s=0;s<CS;s++){
    int acc = 0;
    if (s > 0){
      u32 hreg = h8[(half<<6) | lane];   // wave-uniform half: one word per lane
      #pragma unroll
      for (int k=0;k<64;k++){
        u32 sk = (u32)__builtin_amdgcn_readlane(hreg, k);
        acc = sdot4(wreg[k], sk, acc);
      }
      part_l[tid] = (u32)acc;
    }
    COVBAR();   // partials ready (lgkm-only)
    if (tid < 512){
      float T = 0.f;
      if (s > 0) T = (float)(acc + (int)part_l[tid + 512]) * rs_r;
      float a_cur = a_next;
      if (s < CS-1) a_next = Aenc[(s+1)*CH + tid];
      float h = tanhf(T + al_l[s]*(a_cur + bacc_r) + bsum_r);
      if (s < CS-1){
        int q = (int)rintf(h * 127.f);
        u32 bq = (u32)(q & 255);
        u32 p01 = bq | (__shfl_xor(bq,1) << 8);
        u32 p = p01 | (__shfl_xor(p01,2) << 16);
        if ((tid & 3) == 0) h8[tid >> 2] = p;
        cov_vec[(s+1)*CH + tid] = tanhf(h);   // fire-and-forget
      } else {
        cov_last[tid] = h;
      }
    }
    COVBAR();   // h8 ready for next position
  }
}

// ---------------- host ----------------
extern "C" void kernel_launch(void* const* d_in, const int* in_sizes, int n_in,
                              void* d_out, int out_size, void* d_ws, size_t ws_size,
                              hipStream_t stream){
  (void)in_sizes; (void)n_in; (void)out_size;
  const int*   iseq = (const int*)d_in[0];
  const int*   oseq = (const int*)d_in[1];
  const float* ee   = (const float*)d_in[2];
  const float* de   = (const float*)d_in[3];
  const float* Wih_f=(const float*)d_in[4];  const float* Whh_f=(const float*)d_in[5];
  const float* bih_f=(const float*)d_in[6];  const float* bhh_f=(const float*)d_in[7];
  const float* Wih_b=(const float*)d_in[8];  const float* Whh_b=(const float*)d_in[9];
  const float* bih_b=(const float*)d_in[10]; const float* bhh_b=(const float*)d_in[11];
  const float* Wih_d=(const float*)d_in[12]; const float* Whh_d=(const float*)d_in[13];
  const float* bih_d=(const float*)d_in[14]; const float* bhh_d=(const float*)d_in[15];
  const float* Wih_c=(const float*)d_in[16]; const float* Whh_c=(const float*)d_in[17];
  const float* bih_c=(const float*)d_in[18]; const float* bhh_c=(const float*)d_in[19];
  const float* va   =(const float*)d_in[20]; const float* wa   =(const float*)d_in[21];
  const float* ua   =(const float*)d_in[22]; const float* vc   =(const float*)d_in[23];
  const float* lin_W=(const float*)d_in[24]; const float* lin_b=(const float*)d_in[25];
  float* out = (float*)d_out;
  char* ws = (char*)d_ws;

  size_t off = 0;
  auto A = [&](size_t bytes){ size_t r = off; off = (off + bytes + 255) & ~(size_t)255; return r; };
  size_t o_w8    = A((size_t)CH*128*4);      // i8 coverage weights (256 KB)
  size_t o_rs    = A((size_t)CH*4);
  size_t o_wic16 = A((size_t)CH*CH*2);
  size_t o_xenc = A((size_t)CS*CE*4), o_xdec = A((size_t)CT*CE*4);
  size_t o_gf   = A((size_t)CS*CH3*4), o_gb  = A((size_t)CS*CH3*4);
  size_t o_of   = A((size_t)CS*CH*4),  o_ob  = A((size_t)CS*CH*4);
  size_t o_uae  = A((size_t)CS*CH*4),  o_Ae  = A((size_t)CS*CH*4);
  size_t o_e    = A(CS*4), o_al = A(CS*4), o_ctx = A(CH2*4);
  size_t o_hc   = A(CH*4), o_hn = A(CH*4), o_cl = A(CH*4);
  size_t o_wah  = A(CH*4);
  size_t o_cv   = A((size_t)CS*CH*4);
  size_t o_lwb  = A((size_t)CV*CH3*2);
  bool use16 = (off <= ws_size);

  u32* w8 = (u32*)(ws+o_w8);          float* rs = (float*)(ws+o_rs);
  u16* wic16 = (u16*)(ws+o_wic16);
  float* x_enc = (float*)(ws+o_xenc); float* x_dec = (float*)(ws+o_xdec);
  float* gf = (float*)(ws+o_gf);      float* gb = (float*)(ws+o_gb);
  float* outf = (float*)(ws+o_of);    float* outb = (float*)(ws+o_ob);
  float* ua_enc = (float*)(ws+o_uae); float* Aenc = (float*)(ws+o_Ae);
  float* e = (float*)(ws+o_e);        float* alpha = (float*)(ws+o_al);
  float* ctx = (float*)(ws+o_ctx);
  float* h_carry = (float*)(ws+o_hc); float* h_cur = (float*)(ws+o_hn);
  float* cov_last = (float*)(ws+o_cl);
  float* wah = (float*)(ws+o_wah);
  float* cov_vec = (float*)(ws+o_cv);
  u16* lwb = (u16*)(ws+o_lwb);

  k_init<<<1,256,0,stream>>>(cov_last);
  k_embed<<<CS,256,0,stream>>>(iseq, oseq, ee, de, x_enc, x_dec);
  k_gi<<<(2*CS*CH3)/256,256,0,stream>>>(Wih_f,bih_f,Wih_b,bih_b,x_enc,gf,gb);
  for (int s=0;s<CS;s++)
    k_enc_step<<<16,256,0,stream>>>(s, Whh_f,bhh_f,Whh_b,bhh_b, gf,gb, outf,outb);
  k_prep2<<<(2*CS*CH+CH)/256,256,0,stream>>>(ua, Wih_c, outf, outb, ua_enc, Aenc, h_carry);
  k_cvt_cov<<<(CH*CH)/256,256,0,stream>>>(Wih_c, wic16);
  k_quant<<<CH,64,0,stream>>>(Whh_c, w8, rs);
  if (use16)
    k_cvt<<<2048,256,0,stream>>>(lin_W, lwb, CV*CH3);
  k_wah<<<8,256,0,stream>>>(wa, h_carry, wah);   // initial wah = wa @ h_enc

  for (int t=0;t<CT;t++){
    k_attn<<<CS,256,0,stream>>>(t, vc, va, ua_enc, cov_vec, wah, e);
    k_soft<<<1,128,0,stream>>>(e, outf, outb, alpha, ctx);
    k_gru<<<64,256,0,stream>>>(t, Wih_d,bih_d,Whh_d,bhh_d, ctx, x_dec, h_carry, h_cur);
    if (use16)
      k_tail<1><<<53,1024,0,stream>>>(t, (const void*)lwb, lin_b, h_cur, ctx, out, wa, wah,
                                      w8, rs, wic16, bih_c, bhh_c, Aenc, alpha,
                                      cov_vec, cov_last, h_carry);
    else
      k_tail<0><<<53,1024,0,stream>>>(t, (const void*)lin_W, lin_b, h_cur, ctx, out, wa, wah,
                                      w8, rs, wic16, bih_c, bhh_c, Aenc, alpha,
                                      cov_vec, cov_last, h_carry);
  }
}

// Round 13
// 34612.506 us; speedup vs baseline: 1.1038x; 1.1038x over previous
//
#include <hip/hip_runtime.h>
#include <hip/hip_bf16.h>
#include <hip/hip_fp16.h>
#include <math.h>

#define CS 96      // source len
#define CT 96      // target len
#define CE 256     // embed
#define CH 512     // hidden
#define CH2 1024
#define CH3 1536
#define CV 32000
#define CXD 1280   // E + 2H

typedef unsigned int u32;
typedef unsigned short u16;
typedef unsigned long long u64;
typedef __attribute__((ext_vector_type(4))) int i32x4;

__device__ __forceinline__ float sigm(float x){ return 1.f/(1.f+expf(-x)); }

// packed-fp16 dot2 with fp32 accumulate (bacc prologue only)
__device__ __forceinline__ float dot2f(u32 a, u32 b, float c){
#if __has_builtin(__builtin_amdgcn_fdot2)
  typedef _Float16 hv2 __attribute__((ext_vector_type(2)));
  hv2 x = __builtin_bit_cast(hv2, a), y = __builtin_bit_cast(hv2, b);
  return __builtin_amdgcn_fdot2(x, y, c, false);
#else
  __half2 x = __builtin_bit_cast(__half2, a), y = __builtin_bit_cast(__half2, b);
  return c + __half2float(x.x)*__half2float(y.x) + __half2float(x.y)*__half2float(y.y);
#endif
}

__device__ __forceinline__ u32 packh2(float a, float b){
  return (u32)__half_as_ushort(__float2half(a)) | ((u32)__half_as_ushort(__float2half(b)) << 16);
}

// lgkm-only barrier: drains LDS ops, NOT global stores
#define COVBAR() do{ asm volatile("s_waitcnt lgkmcnt(0)" ::: "memory"); \
                     __builtin_amdgcn_sched_barrier(0); \
                     __builtin_amdgcn_s_barrier(); \
                     __builtin_amdgcn_sched_barrier(0); }while(0)

// ---------------- init: cov_last ----------------
__global__ void k_init(float* cov_last){
  int i = threadIdx.x;
  for (int j = i; j < CH; j += 256) cov_last[j] = 0.f;
}

// ---------------- embedding gathers ----------------
__global__ void k_embed(const int* iseq, const int* oseq, const float* ee, const float* de,
                        float* x_enc, float* x_dec){
  int s = blockIdx.x, d = threadIdx.x;
  x_enc[s*CE+d] = ee[(long)iseq[s]*CE + d];
  x_dec[s*CE+d] = de[(long)oseq[s]*CE + d];
}

// ---------------- encoder input-gate precompute ----------------
__global__ void k_gi(const float* Wf, const float* bf, const float* Wb, const float* bb,
                     const float* x_enc, float* gf, float* gb){
  int idx = blockIdx.x*256 + threadIdx.x;
  int dir = idx / (CS*CH3);
  int rem = idx - dir*(CS*CH3);
  int s = rem / CH3, r = rem - s*CH3;
  const float* W = dir ? Wb : Wf;
  const float* b = dir ? bb : bf;
  const float* x = x_enc + s*CE;
  const float* w = W + (long)r*CE;
  float acc = b[r];
  #pragma unroll 8
  for (int k=0;k<CE;k++) acc += w[k]*x[k];
  (dir ? gb : gf)[s*CH3 + r] = acc;
}

// ---------------- one encoder step ----------------
__global__ void k_enc_step(int s, const float* Whf, const float* bhf, const float* Whb, const float* bhb,
                           const float* gf, const float* gb, float* outf, float* outb){
  int wg = blockIdx.x;
  int dir = wg >> 3;
  int jb = (wg & 7)*64;
  int t = threadIdx.x;
  int j = jb + (t>>2);
  int c0 = (t&3)*128;
  const float* Whh = dir ? Whb : Whf;
  const float* bhh = dir ? bhb : bhf;
  const float* gi  = dir ? gb : gf;
  float* o = dir ? outb : outf;
  int pos = dir ? (CS-1-s) : s;
  const float* hp = (s>0) ? (o + (dir ? (pos+1)*CH : (s-1)*CH)) : nullptr;
  float ar=0.f, az=0.f, an=0.f;
  if (s > 0){
    const float* wr = Whh + (long)j*CH;
    const float* wz = Whh + (long)(j+CH)*CH;
    const float* wn = Whh + (long)(j+2*CH)*CH;
    #pragma unroll 4
    for (int k=c0;k<c0+128;k++){
      float h = hp[k];
      ar += wr[k]*h; az += wz[k]*h; an += wn[k]*h;
    }
  }
  ar += __shfl_xor(ar,1); ar += __shfl_xor(ar,2);
  az += __shfl_xor(az,1); az += __shfl_xor(az,2);
  an += __shfl_xor(an,1); an += __shfl_xor(an,2);
  if ((t&3)==0){
    const float* g = gi + pos*CH3;
    float hpj = (s>0) ? hp[j] : 0.f;
    float r = sigm(g[j]       + ar + bhh[j]);
    float z = sigm(g[j+CH]    + az + bhh[j+CH]);
    float n = tanhf(g[j+2*CH] + r*(an + bhh[j+2*CH]));
    o[pos*CH + j] = (1.f-z)*n + z*hpj;
  }
}

// ---------------- ua_enc / Aenc precompute + h_carry init ----------------
__global__ void k_prep2(const float* ua, const float* Wic, const float* outf, const float* outb,
                        float* ua_enc, float* Aenc, float* h_carry){
  int idx = blockIdx.x*256 + threadIdx.x;
  if (idx < 2*CS*CH){
    int which = idx / (CS*CH);
    int rem = idx - which*(CS*CH);
    int s = rem / CH, r = rem - s*CH;
    const float* of = outf + s*CH;
    const float* ob = outb + s*CH;
    const float* w = which ? (Wic + (long)r*CH3) : (ua + (long)r*CH2);
    float acc = 0.f;
    #pragma unroll 4
    for (int k=0;k<CH;k++) acc += w[k]*of[k];
    #pragma unroll 4
    for (int k=0;k<CH;k++) acc += w[CH+k]*ob[k];
    (which ? Aenc : ua_enc)[s*CH + r] = acc;
  } else if (idx < 2*CS*CH + CH){
    int j = idx - 2*CS*CH;
    h_carry[j] = outf[(CS-1)*CH + j];
  }
}

// ---------------- fp32 -> bf16 (RNE) for lin_W ----------------
__global__ void k_cvt(const float* w, u16* o, int n){
  int i = blockIdx.x*blockDim.x + threadIdx.x;
  int stride = gridDim.x*blockDim.x;
  for (; i<n; i+=stride){
    union { float f; u32 u; } v; v.f = w[i];
    u32 r = (v.u + 0x7fffu + ((v.u>>16)&1u)) >> 16;
    o[i] = (u16)r;
  }
}

// ---------------- fp32 -> fp16 for Wih_c[:,1024:1536] ----------------
__global__ void k_cvt_cov(const float* Wic, u16* wic16){
  int i = blockIdx.x*256 + threadIdx.x;     // CH*CH total
  int r = i >> 9, c = i & 511;
  wic16[i] = __half_as_ushort(__float2half(Wic[(size_t)r*CH3 + CH2 + c]));
}

// ---------------- Whh_c -> i8 packed in MFMA A-fragment layout ----------------
// A-frag (16x64 i8 tile): lane l holds row=tile_r*16+(l&15), k=tile_k*64+(l>>4)*16+byte.
// w8m[tile*64 + lane] = uint4 (16 bytes along k).  tile = (row>>4)*8 + kb.
__global__ void k_quant(const float* Whc, uint4* w8m, float* rs){
  int r = blockIdx.x;          // 512 blocks x 64 threads
  int l = threadIdx.x;
  const float* wr = Whc + (size_t)r*CH;
  float m = 0.f;
  for (int k=l; k<CH; k+=64) m = fmaxf(m, fabsf(wr[k]));
  for (int d=1; d<64; d<<=1) m = fmaxf(m, __shfl_xor(m,d));
  float sc = (m > 0.f) ? (127.f/m) : 0.f;
  if (l < 32){
    int kb = l>>2, q = l&3;
    u32 wv[4];
    #pragma unroll
    for (int wi=0;wi<4;wi++){
      u32 p = 0;
      #pragma unroll
      for (int j=0;j<4;j++){
        int v = (int)rintf(wr[kb*64 + q*16 + wi*4 + j]*sc);
        v = max(-127, min(127, v));
        p |= (u32)(v & 255) << (8*j);
      }
      wv[wi] = p;
    }
    int tile = (r>>4)*8 + kb;
    int lane = q*16 + (r&15);
    w8m[(size_t)tile*64 + lane] = make_uint4(wv[0],wv[1],wv[2],wv[3]);
  }
  if (l==0) rs[r] = m/(127.f*127.f);
}

// ---------------- wah = wa @ h (pre-loop only) ----------------
__global__ void k_wah(const float* wa, const float* h, float* wah){
  int j = blockIdx.x*64 + (threadIdx.x>>2);
  int c0 = (threadIdx.x&3)*128;
  const float* w = wa + (long)j*CH;
  float acc = 0.f;
  #pragma unroll 4
  for (int k=c0;k<c0+128;k++) acc += w[k]*h[k];
  acc += __shfl_xor(acc,1); acc += __shfl_xor(acc,2);
  if ((threadIdx.x&3)==0) wah[j] = acc;
}

// ---------------- attention scores e[s] ----------------
__global__ void k_attn(int t, const float* vc, const float* va,
                       const float* ua_enc, const float* cov_vec, const float* wah, float* e){
  int s = blockIdx.x, tid = threadIdx.x;
  __shared__ float red[4];
  float sum = 0.f;
  #pragma unroll
  for (int jj=0;jj<2;jj++){
    int j = tid + jj*256;
    float acc = ua_enc[s*CH + j] + wah[j];
    if (t > 0){
      const float* v = vc + (long)j*CH;
      const float* cvs = cov_vec + s*CH;
      #pragma unroll 4
      for (int k=0;k<CH;k++) acc += v[k]*cvs[k];
    }
    sum += va[j]*tanhf(acc);
  }
  for (int m=1;m<64;m<<=1) sum += __shfl_xor(sum,m);
  if ((tid&63)==0) red[tid>>6] = sum;
  __syncthreads();
  if (tid==0) e[s] = red[0]+red[1]+red[2]+red[3];
}

// ---------------- softmax + context ----------------
__global__ void k_soft(const float* e, const float* outf, const float* outb, float* alpha, float* ctx){
  int tid = threadIdx.x; // 128
  __shared__ float al[CS];
  __shared__ float rmax[2], rsum[2];
  float v = (tid<CS) ? e[tid] : -1e30f;
  float m = v;
  for (int k=1;k<64;k<<=1) m = fmaxf(m, __shfl_xor(m,k));
  if ((tid&63)==0) rmax[tid>>6] = m;
  __syncthreads();
  float gm = fmaxf(rmax[0], rmax[1]);
  float ex = (tid<CS) ? expf(v-gm) : 0.f;
  float sm2 = ex;
  for (int k=1;k<64;k<<=1) sm2 += __shfl_xor(sm2,k);
  if ((tid&63)==0) rsum[tid>>6] = sm2;
  __syncthreads();
  float inv = 1.f/(rsum[0]+rsum[1]);
  if (tid<CS){ float a = ex*inv; al[tid] = a; alpha[tid] = a; }
  __syncthreads();
  #pragma unroll
  for (int k=0;k<8;k++){
    int d = k*128 + tid;
    const float* src = (d<CH) ? outf : outb;
    int dd = (d<CH) ? d : d-CH;
    float acc = 0.f;
    for (int s2=0;s2<CS;s2++) acc += al[s2]*src[s2*CH+dd];
    ctx[d] = acc;
  }
}

// ---------------- decoder GRU ----------------
__global__ void k_gru(int t, const float* Wi, const float* bi, const float* Wh, const float* bh,
                      const float* ctx, const float* x_dec, const float* h_carry, float* h_cur){
  int wg = blockIdx.x, tid = threadIdx.x;
  int j = wg*8 + (tid>>5);
  int ln = tid&31;
  const float* xd = x_dec + t*CE;
  float ar=0.f, az=0.f, an=0.f;
  {
    int c0 = ln*40;
    const float* wr = Wi + (long)j*CXD;
    const float* wz = Wi + (long)(j+CH)*CXD;
    const float* wn = Wi + (long)(j+2*CH)*CXD;
    for (int k=c0;k<c0+40;k++){
      float x = (k<CH2) ? ctx[k] : xd[k-CH2];
      ar += wr[k]*x; az += wz[k]*x; an += wn[k]*x;
    }
  }
  float hr=0.f, hz=0.f, hn2=0.f;
  {
    int c0 = ln*16;
    const float* wr = Wh + (long)j*CH;
    const float* wz = Wh + (long)(j+CH)*CH;
    const float* wn = Wh + (long)(j+2*CH)*CH;
    for (int k=c0;k<c0+16;k++){
      float hv = h_carry[k];
      hr += wr[k]*hv; hz += wz[k]*hv; hn2 += wn[k]*hv;
    }
  }
  for (int m=1;m<32;m<<=1){
    ar+=__shfl_xor(ar,m); az+=__shfl_xor(az,m); an+=__shfl_xor(an,m);
    hr+=__shfl_xor(hr,m); hz+=__shfl_xor(hz,m); hn2+=__shfl_xor(hn2,m);
  }
  if (ln==0){
    float hprev = h_carry[j];
    float r = sigm(ar + bi[j]       + hr + bh[j]);
    float z = sigm(az + bi[j+CH]    + hz + bh[j+CH]);
    float n = tanhf(an + bi[j+2*CH] + r*(hn2 + bh[j+2*CH]));
    h_cur[j] = (1.f-z)*n + z*hprev;
  }
}

// ---------------- fused tail: block 0 cov SOLO (MFMA i8) | 1,2 wah | 3..52 logits ----------------
template<int BF16>
__launch_bounds__(1024, 4)
__global__ void k_tail(int t, const void* Wv, const float* lb, const float* h_cur, const float* ctx,
                       float* out, const float* wa, float* wah,
                       const uint4* w8m, const float* rs, const u16* wic16,
                       const float* bic, const float* bhc,
                       const float* Aenc, const float* alpha,
                       float* cov_vec, float* cov_last, float* h_carry){
  int b = blockIdx.x, tid = threadIdx.x;

  if (b >= 3){
    // ---- logits: 50 blocks x 16 waves = 800 row-walkers ----
    int ln = tid&63;
    int gw = (b-3)*16 + (tid>>6);   // 0..799
    float x[24];
    #pragma unroll
    for (int k=0;k<24;k++){
      int c = k*64 + ln;
      x[k] = (c<CH) ? h_cur[c] : ctx[c-CH];
    }
    for (int r=gw; r<CV; r+=800){
      float acc = 0.f;
      if (BF16){
        const u16* w = (const u16*)Wv + (long)r*CH3;
        #pragma unroll
        for (int k=0;k<24;k++){
          u32 u = (u32)w[k*64+ln] << 16;
          acc += __uint_as_float(u)*x[k];
        }
      } else {
        const float* w = (const float*)Wv + (long)r*CH3;
        #pragma unroll
        for (int k=0;k<24;k++) acc += w[k*64+ln]*x[k];
      }
      for (int m=1;m<64;m<<=1) acc += __shfl_xor(acc,m);
      if (ln==0) out[(long)t*CV + r] = acc + lb[r];
    }
    return;
  }

  if (b >= 1){
    // ---- wah = wa @ h_cur for next step (skip at t=0: keeps wa@h_enc) ----
    if (t > 0){
      int j = (b-1)*256 + (tid>>2);
      int cq = (tid&3)*128;
      const float* w = wa + (long)j*CH;
      float acc = 0.f;
      #pragma unroll 4
      for (int k=cq;k<cq+128;k++) acc += w[k]*h_cur[k];
      acc += __shfl_xor(acc,1); acc += __shfl_xor(acc,2);
      if ((tid&3)==0) wah[j] = acc;
    }
    return;
  }

  // ================= coverage solo: ONE CU, MFMA i8 16x16x64, no cross-WG sync =================
  const float* h_dec = (t==0) ? h_carry : h_cur;
  int w = tid >> 6;          // wave 0..15 (owns rows 32w..32w+31)
  int l = tid & 63;

  __shared__ u32 part_l[1024];             // D ints / bacc f32 partials
  __shared__ __align__(16) u32 h8w[128];   // h as i8, word j = rows 4j..4j+3
  __shared__ u32 hd16[256];                // h_dec fp16 pairs (bacc)
  __shared__ float al_l[CS];

  if (tid < CS) al_l[tid] = alpha[tid];
  if (tid < 256) hd16[tid] = packh2(h_dec[2*tid], h_dec[2*tid+1]);
  __syncthreads();   // hd16 + al ready

  // ---- bacc partials: thread=(row tid>>1, seg tid&1 of 256 cols), fp16 dot ----
  {
    int rw = tid >> 1, sg = tid & 1;
    const uint4* bw = (const uint4*)(wic16 + (size_t)rw*CH + sg*256);
    float bp = 0.f;
    #pragma unroll
    for (int k=0;k<32;k++){
      uint4 wv = bw[k];
      const uint4 hv = *(const uint4*)&hd16[sg*128 + 4*k];
      bp = dot2f(wv.x,hv.x,bp); bp = dot2f(wv.y,hv.y,bp);
      bp = dot2f(wv.z,hv.z,bp); bp = dot2f(wv.w,hv.w,bp);
      if ((k&3)==3) asm volatile("" ::: "memory");
    }
    part_l[tid] = __float_as_uint(bp);
  }

  // ---- A fragments: 2 row-tiles x 8 k-tiles, 16 uint4 = 64 VGPRs ----
  i32x4 af0[8], af1[8];
  {
    const i32x4* wp = (const i32x4*)w8m;
    #pragma unroll
    for (int kb=0;kb<8;kb++){
      af0[kb] = wp[((size_t)((2*w+0)*8+kb))*64 + l];
      af1[kb] = wp[((size_t)((2*w+1)*8+kb))*64 + l];
      asm volatile("" ::: "memory");   // cap in-flight loads (spill guard)
    }
  }
  __syncthreads();   // bacc partials ready

  float bacc_r=0.f, bsum_r=0.f, rs_r=0.f, a_next=0.f;
  if (tid < 512){
    bacc_r = __uint_as_float(part_l[2*tid]) + __uint_as_float(part_l[2*tid+1]);
    bsum_r = bic[tid] + bhc[tid];
    rs_r = rs[tid];
    a_next = Aenc[tid];
    cov_vec[tid] = tanhf(cov_last[tid]);   // cov_vec position-0 entry
    if (t > 0) h_carry[tid] = h_dec[tid];  // commit carry
  }
  __syncthreads();   // part_l free for reuse

  for (int s=0;s<CS;s++){
    if (s > 0){
      i32x4 acc0 = {0,0,0,0}, acc1 = {0,0,0,0};
      #pragma unroll
      for (int kb=0;kb<8;kb++){
        // B frag: 16 h-bytes at k=kb*64+(l>>4)*16, broadcast across the 16 cols
        i32x4 bfr = *(const i32x4*)&h8w[kb*16 + (l>>4)*4];
        acc0 = __builtin_amdgcn_mfma_i32_16x16x64_i8(af0[kb], bfr, acc0, 0, 0, 0);
        acc1 = __builtin_amdgcn_mfma_i32_16x16x64_i8(af1[kb], bfr, acc1, 0, 0, 0);
      }
      if ((l & 15) == 0){      // col 0 lanes hold D rows (l>>4)*4+r
        int rq = l >> 4;
        #pragma unroll
        for (int r4=0;r4<4;r4++){
          part_l[(2*w+0)*16 + rq*4 + r4] = (u32)acc0[r4];
          part_l[(2*w+1)*16 + rq*4 + r4] = (u32)acc1[r4];
        }
      }
    }
    COVBAR();   // D ints in LDS (lgkm-only)
    if (tid < 512){
      float T = (s > 0) ? (float)(int)part_l[tid] * rs_r : 0.f;
      float a_cur = a_next;
      if (s < CS-1) a_next = Aenc[(s+1)*CH + tid];
      float h = tanhf(T + al_l[s]*(a_cur + bacc_r) + bsum_r);
      if (s < CS-1){
        int q = (int)rintf(h * 127.f);
        u32 bq = (u32)(q & 255);
        u32 p01 = bq | (__shfl_xor(bq,1) << 8);
        u32 p = p01 | (__shfl_xor(p01,2) << 16);
        if ((tid & 3) == 0) h8w[tid >> 2] = p;
        cov_vec[(s+1)*CH + tid] = tanhf(h);   // fire-and-forget
      } else {
        cov_last[tid] = h;
      }
    }
    COVBAR();   // h8w ready for next position
  }
}

// ---------------- host ----------------
extern "C" void kernel_launch(void* const* d_in, const int* in_sizes, int n_in,
                              void* d_out, int out_size, void* d_ws, size_t ws_size,
                              hipStream_t stream){
  (void)in_sizes; (void)n_in; (void)out_size;
  const int*   iseq = (const int*)d_in[0];
  const int*   oseq = (const int*)d_in[1];
  const float* ee   = (const float*)d_in[2];
  const float* de   = (const float*)d_in[3];
  const float* Wih_f=(const float*)d_in[4];  const float* Whh_f=(const float*)d_in[5];
  const float* bih_f=(const float*)d_in[6];  const float* bhh_f=(const float*)d_in[7];
  const float* Wih_b=(const float*)d_in[8];  const float* Whh_b=(const float*)d_in[9];
  const float* bih_b=(const float*)d_in[10]; const float* bhh_b=(const float*)d_in[11];
  const float* Wih_d=(const float*)d_in[12]; const float* Whh_d=(const float*)d_in[13];
  const float* bih_d=(const float*)d_in[14]; const float* bhh_d=(const float*)d_in[15];
  const float* Wih_c=(const float*)d_in[16]; const float* Whh_c=(const float*)d_in[17];
  const float* bih_c=(const float*)d_in[18]; const float* bhh_c=(const float*)d_in[19];
  const float* va   =(const float*)d_in[20]; const float* wa   =(const float*)d_in[21];
  const float* ua   =(const float*)d_in[22]; const float* vc   =(const float*)d_in[23];
  const float* lin_W=(const float*)d_in[24]; const float* lin_b=(const float*)d_in[25];
  float* out = (float*)d_out;
  char* ws = (char*)d_ws;

  size_t off = 0;
  auto A = [&](size_t bytes){ size_t r = off; off = (off + bytes + 255) & ~(size_t)255; return r; };
  size_t o_w8m   = A((size_t)CH*128*4);      // i8 MFMA A-frags (256 KB)
  size_t o_rs    = A((size_t)CH*4);
  size_t o_wic16 = A((size_t)CH*CH*2);
  size_t o_xenc = A((size_t)CS*CE*4), o_xdec = A((size_t)CT*CE*4);
  size_t o_gf   = A((size_t)CS*CH3*4), o_gb  = A((size_t)CS*CH3*4);
  size_t o_of   = A((size_t)CS*CH*4),  o_ob  = A((size_t)CS*CH*4);
  size_t o_uae  = A((size_t)CS*CH*4),  o_Ae  = A((size_t)CS*CH*4);
  size_t o_e    = A(CS*4), o_al = A(CS*4), o_ctx = A(CH2*4);
  size_t o_hc   = A(CH*4), o_hn = A(CH*4), o_cl = A(CH*4);
  size_t o_wah  = A(CH*4);
  size_t o_cv   = A((size_t)CS*CH*4);
  size_t o_lwb  = A((size_t)CV*CH3*2);
  bool use16 = (off <= ws_size);

  uint4* w8m = (uint4*)(ws+o_w8m);    float* rs = (float*)(ws+o_rs);
  u16* wic16 = (u16*)(ws+o_wic16);
  float* x_enc = (float*)(ws+o_xenc); float* x_dec = (float*)(ws+o_xdec);
  float* gf = (float*)(ws+o_gf);      float* gb = (float*)(ws+o_gb);
  float* outf = (float*)(ws+o_of);    float* outb = (float*)(ws+o_ob);
  float* ua_enc = (float*)(ws+o_uae); float* Aenc = (float*)(ws+o_Ae);
  float* e = (float*)(ws+o_e);        float* alpha = (float*)(ws+o_al);
  float* ctx = (float*)(ws+o_ctx);
  float* h_carry = (float*)(ws+o_hc); float* h_cur = (float*)(ws+o_hn);
  float* cov_last = (float*)(ws+o_cl);
  float* wah = (float*)(ws+o_wah);
  float* cov_vec = (float*)(ws+o_cv);
  u16* lwb = (u16*)(ws+o_lwb);

  k_init<<<1,256,0,stream>>>(cov_last);
  k_embed<<<CS,256,0,stream>>>(iseq, oseq, ee, de, x_enc, x_dec);
  k_gi<<<(2*CS*CH3)/256,256,0,stream>>>(Wih_f,bih_f,Wih_b,bih_b,x_enc,gf,gb);
  for (int s=0;s<CS;s++)
    k_enc_step<<<16,256,0,stream>>>(s, Whh_f,bhh_f,Whh_b,bhh_b, gf,gb, outf,outb);
  k_prep2<<<(2*CS*CH+CH)/256,256,0,stream>>>(ua, Wih_c, outf, outb, ua_enc, Aenc, h_carry);
  k_cvt_cov<<<(CH*CH)/256,256,0,stream>>>(Wih_c, wic16);
  k_quant<<<CH,64,0,stream>>>(Whh_c, w8m, rs);
  if (use16)
    k_cvt<<<2048,256,0,stream>>>(lin_W, lwb, CV*CH3);
  k_wah<<<8,256,0,stream>>>(wa, h_carry, wah);   // initial wah = wa @ h_enc

  for (int t=0;t<CT;t++){
    k_attn<<<CS,256,0,stream>>>(t, vc, va, ua_enc, cov_vec, wah, e);
    k_soft<<<1,128,0,stream>>>(e, outf, outb, alpha, ctx);
    k_gru<<<64,256,0,stream>>>(t, Wih_d,bih_d,Whh_d,bhh_d, ctx, x_dec, h_carry, h_cur);
    if (use16)
      k_tail<1><<<53,1024,0,stream>>>(t, (const void*)lwb, lin_b, h_cur, ctx, out, wa, wah,
                                      w8m, rs, wic16, bih_c, bhh_c, Aenc, alpha,
                                      cov_vec, cov_last, h_carry);
    else
      k_tail<0><<<53,1024,0,stream>>>(t, (const void*)lin_W, lin_b, h_cur, ctx, out, wa, wah,
                                      w8m, rs, wic16, bih_c, bhh_c, Aenc, alpha,
                                      cov_vec, cov_last, h_carry);
  }
}

// Round 14
// 34136.093 us; speedup vs baseline: 1.1192x; 1.0140x over previous
//
#include <hip/hip_runtime.h>
#include <hip/hip_bf16.h>
#include <hip/hip_fp16.h>
#include <math.h>

#define CS 96      // source len
#define CT 96      // target len
#define CE 256     // embed
#define CH 512     // hidden
#define CH2 1024
#define CH3 1536
#define CV 32000
#define CXD 1280   // E + 2H

typedef unsigned int u32;
typedef unsigned short u16;
typedef unsigned long long u64;
typedef __attribute__((ext_vector_type(4))) int i32x4;

__device__ __forceinline__ float sigm(float x){ return 1.f/(1.f+expf(-x)); }

// packed-fp16 dot2 with fp32 accumulate (bacc prologue only)
__device__ __forceinline__ float dot2f(u32 a, u32 b, float c){
#if __has_builtin(__builtin_amdgcn_fdot2)
  typedef _Float16 hv2 __attribute__((ext_vector_type(2)));
  hv2 x = __builtin_bit_cast(hv2, a), y = __builtin_bit_cast(hv2, b);
  return __builtin_amdgcn_fdot2(x, y, c, false);
#else
  __half2 x = __builtin_bit_cast(__half2, a), y = __builtin_bit_cast(__half2, b);
  return c + __half2float(x.x)*__half2float(y.x) + __half2float(x.y)*__half2float(y.y);
#endif
}

__device__ __forceinline__ u32 packh2(float a, float b){
  return (u32)__half_as_ushort(__float2half(a)) | ((u32)__half_as_ushort(__float2half(b)) << 16);
}

// lgkm-only barrier: drains LDS ops, NOT global stores
#define COVBAR() do{ asm volatile("s_waitcnt lgkmcnt(0)" ::: "memory"); \
                     __builtin_amdgcn_sched_barrier(0); \
                     __builtin_amdgcn_s_barrier(); \
                     __builtin_amdgcn_sched_barrier(0); }while(0)

// ---------------- init: cov_last ----------------
__global__ void k_init(float* cov_last){
  int i = threadIdx.x;
  for (int j = i; j < CH; j += 256) cov_last[j] = 0.f;
}

// ---------------- embedding gathers ----------------
__global__ void k_embed(const int* iseq, const int* oseq, const float* ee, const float* de,
                        float* x_enc, float* x_dec){
  int s = blockIdx.x, d = threadIdx.x;
  x_enc[s*CE+d] = ee[(long)iseq[s]*CE + d];
  x_dec[s*CE+d] = de[(long)oseq[s]*CE + d];
}

// ---------------- encoder input-gate precompute ----------------
__global__ void k_gi(const float* Wf, const float* bf, const float* Wb, const float* bb,
                     const float* x_enc, float* gf, float* gb){
  int idx = blockIdx.x*256 + threadIdx.x;
  int dir = idx / (CS*CH3);
  int rem = idx - dir*(CS*CH3);
  int s = rem / CH3, r = rem - s*CH3;
  const float* W = dir ? Wb : Wf;
  const float* b = dir ? bb : bf;
  const float* x = x_enc + s*CE;
  const float* w = W + (long)r*CE;
  float acc = b[r];
  #pragma unroll 8
  for (int k=0;k<CE;k++) acc += w[k]*x[k];
  (dir ? gb : gf)[s*CH3 + r] = acc;
}

// ---------------- one encoder step ----------------
__global__ void k_enc_step(int s, const float* Whf, const float* bhf, const float* Whb, const float* bhb,
                           const float* gf, const float* gb, float* outf, float* outb){
  int wg = blockIdx.x;
  int dir = wg >> 3;
  int jb = (wg & 7)*64;
  int t = threadIdx.x;
  int j = jb + (t>>2);
  int c0 = (t&3)*128;
  const float* Whh = dir ? Whb : Whf;
  const float* bhh = dir ? bhb : bhf;
  const float* gi  = dir ? gb : gf;
  float* o = dir ? outb : outf;
  int pos = dir ? (CS-1-s) : s;
  const float* hp = (s>0) ? (o + (dir ? (pos+1)*CH : (s-1)*CH)) : nullptr;
  float ar=0.f, az=0.f, an=0.f;
  if (s > 0){
    const float* wr = Whh + (long)j*CH;
    const float* wz = Whh + (long)(j+CH)*CH;
    const float* wn = Whh + (long)(j+2*CH)*CH;
    #pragma unroll 4
    for (int k=c0;k<c0+128;k++){
      float h = hp[k];
      ar += wr[k]*h; az += wz[k]*h; an += wn[k]*h;
    }
  }
  ar += __shfl_xor(ar,1); ar += __shfl_xor(ar,2);
  az += __shfl_xor(az,1); az += __shfl_xor(az,2);
  an += __shfl_xor(an,1); an += __shfl_xor(an,2);
  if ((t&3)==0){
    const float* g = gi + pos*CH3;
    float hpj = (s>0) ? hp[j] : 0.f;
    float r = sigm(g[j]       + ar + bhh[j]);
    float z = sigm(g[j+CH]    + az + bhh[j+CH]);
    float n = tanhf(g[j+2*CH] + r*(an + bhh[j+2*CH]));
    o[pos*CH + j] = (1.f-z)*n + z*hpj;
  }
}

// ---------------- ua_enc / Aenc precompute + h_carry init ----------------
__global__ void k_prep2(const float* ua, const float* Wic, const float* outf, const float* outb,
                        float* ua_enc, float* Aenc, float* h_carry){
  int idx = blockIdx.x*256 + threadIdx.x;
  if (idx < 2*CS*CH){
    int which = idx / (CS*CH);
    int rem = idx - which*(CS*CH);
    int s = rem / CH, r = rem - s*CH;
    const float* of = outf + s*CH;
    const float* ob = outb + s*CH;
    const float* w = which ? (Wic + (long)r*CH3) : (ua + (long)r*CH2);
    float acc = 0.f;
    #pragma unroll 4
    for (int k=0;k<CH;k++) acc += w[k]*of[k];
    #pragma unroll 4
    for (int k=0;k<CH;k++) acc += w[CH+k]*ob[k];
    (which ? Aenc : ua_enc)[s*CH + r] = acc;
  } else if (idx < 2*CS*CH + CH){
    int j = idx - 2*CS*CH;
    h_carry[j] = outf[(CS-1)*CH + j];
  }
}

// ---------------- fp32 -> bf16 (RNE) for lin_W ----------------
__global__ void k_cvt(const float* w, u16* o, int n){
  int i = blockIdx.x*blockDim.x + threadIdx.x;
  int stride = gridDim.x*blockDim.x;
  for (; i<n; i+=stride){
    union { float f; u32 u; } v; v.f = w[i];
    u32 r = (v.u + 0x7fffu + ((v.u>>16)&1u)) >> 16;
    o[i] = (u16)r;
  }
}

// ---------------- Wih_c[:,1024:1536] -> packed-transposed fp16: wic16P[kp*512+r] ----------------
__global__ void k_cvt_cov(const float* Wic, u32* wic16P){
  int i = blockIdx.x*256 + threadIdx.x;     // 256*512 total
  int kp = i >> 9, r = i & 511;
  float a = Wic[(size_t)r*CH3 + CH2 + 2*kp];
  float b = Wic[(size_t)r*CH3 + CH2 + 2*kp + 1];
  wic16P[(size_t)kp*512 + r] = packh2(a, b);
}

// ---------------- Whh_c -> i8 packed in MFMA A-fragment layout ----------------
// A-frag (16x64 i8 tile): lane l holds row=tile_r*16+(l&15), k=tile_k*64+(l>>4)*16+byte.
// w8m[tile*64 + lane] = uint4.  tile = (row>>4)*8 + kb.
__global__ void k_quant(const float* Whc, uint4* w8m, float* rs){
  int r = blockIdx.x;          // 512 blocks x 64 threads
  int l = threadIdx.x;
  const float* wr = Whc + (size_t)r*CH;
  float m = 0.f;
  for (int k=l; k<CH; k+=64) m = fmaxf(m, fabsf(wr[k]));
  for (int d=1; d<64; d<<=1) m = fmaxf(m, __shfl_xor(m,d));
  float sc = (m > 0.f) ? (127.f/m) : 0.f;
  if (l < 32){
    int kb = l>>2, q = l&3;
    u32 wv[4];
    #pragma unroll
    for (int wi=0;wi<4;wi++){
      u32 p = 0;
      #pragma unroll
      for (int j=0;j<4;j++){
        int v = (int)rintf(wr[kb*64 + q*16 + wi*4 + j]*sc);
        v = max(-127, min(127, v));
        p |= (u32)(v & 255) << (8*j);
      }
      wv[wi] = p;
    }
    int tile = (r>>4)*8 + kb;
    int lane = q*16 + (r&15);
    w8m[(size_t)tile*64 + lane] = make_uint4(wv[0],wv[1],wv[2],wv[3]);
  }
  if (l==0) rs[r] = m/(127.f*127.f);
}

// ---------------- wah = wa @ h (pre-loop only) ----------------
__global__ void k_wah(const float* wa, const float* h, float* wah){
  int j = blockIdx.x*64 + (threadIdx.x>>2);
  int c0 = (threadIdx.x&3)*128;
  const float* w = wa + (long)j*CH;
  float acc = 0.f;
  #pragma unroll 4
  for (int k=c0;k<c0+128;k++) acc += w[k]*h[k];
  acc += __shfl_xor(acc,1); acc += __shfl_xor(acc,2);
  if ((threadIdx.x&3)==0) wah[j] = acc;
}

// ---------------- attention scores e[s] ----------------
__global__ void k_attn(int t, const float* vc, const float* va,
                       const float* ua_enc, const float* cov_vec, const float* wah, float* e){
  int s = blockIdx.x, tid = threadIdx.x;
  __shared__ float red[4];
  float sum = 0.f;
  #pragma unroll
  for (int jj=0;jj<2;jj++){
    int j = tid + jj*256;
    float acc = ua_enc[s*CH + j] + wah[j];
    if (t > 0){
      const float* v = vc + (long)j*CH;
      const float* cvs = cov_vec + s*CH;
      #pragma unroll 4
      for (int k=0;k<CH;k++) acc += v[k]*cvs[k];
    }
    sum += va[j]*tanhf(acc);
  }
  for (int m=1;m<64;m<<=1) sum += __shfl_xor(sum,m);
  if ((tid&63)==0) red[tid>>6] = sum;
  __syncthreads();
  if (tid==0) e[s] = red[0]+red[1]+red[2]+red[3];
}

// ---------------- softmax + context ----------------
__global__ void k_soft(const float* e, const float* outf, const float* outb, float* alpha, float* ctx){
  int tid = threadIdx.x; // 128
  __shared__ float al[CS];
  __shared__ float rmax[2], rsum[2];
  float v = (tid<CS) ? e[tid] : -1e30f;
  float m = v;
  for (int k=1;k<64;k<<=1) m = fmaxf(m, __shfl_xor(m,k));
  if ((tid&63)==0) rmax[tid>>6] = m;
  __syncthreads();
  float gm = fmaxf(rmax[0], rmax[1]);
  float ex = (tid<CS) ? expf(v-gm) : 0.f;
  float sm2 = ex;
  for (int k=1;k<64;k<<=1) sm2 += __shfl_xor(sm2,k);
  if ((tid&63)==0) rsum[tid>>6] = sm2;
  __syncthreads();
  float inv = 1.f/(rsum[0]+rsum[1]);
  if (tid<CS){ float a = ex*inv; al[tid] = a; alpha[tid] = a; }
  __syncthreads();
  #pragma unroll
  for (int k=0;k<8;k++){
    int d = k*128 + tid;
    const float* src = (d<CH) ? outf : outb;
    int dd = (d<CH) ? d : d-CH;
    float acc = 0.f;
    for (int s2=0;s2<CS;s2++) acc += al[s2]*src[s2*CH+dd];
    ctx[d] = acc;
  }
}

// ---------------- decoder GRU ----------------
__global__ void k_gru(int t, const float* Wi, const float* bi, const float* Wh, const float* bh,
                      const float* ctx, const float* x_dec, const float* h_carry, float* h_cur){
  int wg = blockIdx.x, tid = threadIdx.x;
  int j = wg*8 + (tid>>5);
  int ln = tid&31;
  const float* xd = x_dec + t*CE;
  float ar=0.f, az=0.f, an=0.f;
  {
    int c0 = ln*40;
    const float* wr = Wi + (long)j*CXD;
    const float* wz = Wi + (long)(j+CH)*CXD;
    const float* wn = Wi + (long)(j+2*CH)*CXD;
    for (int k=c0;k<c0+40;k++){
      float x = (k<CH2) ? ctx[k] : xd[k-CH2];
      ar += wr[k]*x; az += wz[k]*x; an += wn[k]*x;
    }
  }
  float hr=0.f, hz=0.f, hn2=0.f;
  {
    int c0 = ln*16;
    const float* wr = Wh + (long)j*CH;
    const float* wz = Wh + (long)(j+CH)*CH;
    const float* wn = Wh + (long)(j+2*CH)*CH;
    for (int k=c0;k<c0+16;k++){
      float hv = h_carry[k];
      hr += wr[k]*hv; hz += wz[k]*hv; hn2 += wn[k]*hv;
    }
  }
  for (int m=1;m<32;m<<=1){
    ar+=__shfl_xor(ar,m); az+=__shfl_xor(az,m); an+=__shfl_xor(an,m);
    hr+=__shfl_xor(hr,m); hz+=__shfl_xor(hz,m); hn2+=__shfl_xor(hn2,m);
  }
  if (ln==0){
    float hprev = h_carry[j];
    float r = sigm(ar + bi[j]       + hr + bh[j]);
    float z = sigm(az + bi[j+CH]    + hz + bh[j+CH]);
    float n = tanhf(an + bi[j+2*CH] + r*(hn2 + bh[j+2*CH]));
    h_cur[j] = (1.f-z)*n + z*hprev;
  }
}

// ---------------- fused tail (512-thread blocks): 0 cov SOLO | 1,2 wah | 3..102 logits ----------------
template<int BF16>
__launch_bounds__(512, 2)
__global__ void k_tail(int t, const void* Wv, const float* lb, const float* h_cur, const float* ctx,
                       float* out, const float* wa, float* wah,
                       const uint4* w8m, const float* rs, const u32* wic16P,
                       const float* bic, const float* bhc,
                       const float* Aenc, const float* alpha,
                       float* cov_vec, float* cov_last, float* h_carry){
  int b = blockIdx.x, tid = threadIdx.x;

  if (b >= 3){
    // ---- logits: 100 blocks x 8 waves = 800 row-walkers ----
    int ln = tid&63;
    int gw = (b-3)*8 + (tid>>6);   // 0..799
    float x[24];
    #pragma unroll
    for (int k=0;k<24;k++){
      int c = k*64 + ln;
      x[k] = (c<CH) ? h_cur[c] : ctx[c-CH];
    }
    for (int r=gw; r<CV; r+=800){
      float acc = 0.f;
      if (BF16){
        const u16* w = (const u16*)Wv + (long)r*CH3;
        #pragma unroll
        for (int k=0;k<24;k++){
          u32 u = (u32)w[k*64+ln] << 16;
          acc += __uint_as_float(u)*x[k];
        }
      } else {
        const float* w = (const float*)Wv + (long)r*CH3;
        #pragma unroll
        for (int k=0;k<24;k++) acc += w[k*64+ln]*x[k];
      }
      for (int m=1;m<64;m<<=1) acc += __shfl_xor(acc,m);
      if (ln==0) out[(long)t*CV + r] = acc + lb[r];
    }
    return;
  }

  if (b >= 1){
    // ---- wah = wa @ h_cur for next step (skip at t=0: keeps wa@h_enc) ----
    if (t > 0){
      int j = (b-1)*256 + (tid>>1);
      int cq = (tid&1)*256;
      const float* w = wa + (long)j*CH;
      float acc = 0.f;
      #pragma unroll 4
      for (int k=cq;k<cq+256;k++) acc += w[k]*h_cur[k];
      acc += __shfl_xor(acc,1);
      if ((tid&1)==0) wah[j] = acc;
    }
    return;
  }

  // ================= coverage solo: 512 threads, 8 waves, 256-VGPR budget, MFMA i8 =================
  const float* h_dec = (t==0) ? h_carry : h_cur;
  int w = tid >> 6;          // wave 0..7 (owns row-tiles 4w..4w+3 = rows 64w..64w+63)
  int l = tid & 63;

  __shared__ u32 part_l[512];              // D ints (row-indexed)
  __shared__ __align__(16) u32 h8w[128];   // h as i8, word j = rows 4j..4j+3
  __shared__ u32 hd16[256];                // h_dec fp16 pairs (bacc)
  __shared__ float al_l[CS];

  if (tid < CS) al_l[tid] = alpha[tid];
  if (tid < 256) hd16[tid] = packh2(h_dec[2*tid], h_dec[2*tid+1]);
  __syncthreads();   // hd16 + al ready

  // ---- bacc: thread = row, coalesced packed-transposed loads ----
  float bacc_r = 0.f;
  {
    const u32* bw = wic16P + tid;
    #pragma unroll 8
    for (int kp=0;kp<256;kp++)
      bacc_r = dot2f(bw[(size_t)kp*512], hd16[kp], bacc_r);
  }

  // ---- A fragments: 4 row-tiles x 8 k-tiles = 32 uint4 = 128 VGPRs ----
  i32x4 af[4][8];
  {
    const i32x4* wp = (const i32x4*)w8m;
    #pragma unroll
    for (int j=0;j<4;j++){
      #pragma unroll
      for (int kb=0;kb<8;kb++)
        af[j][kb] = wp[((size_t)((4*w+j)*8+kb))*64 + l];
      asm volatile("" ::: "memory");   // cap in-flight loads (spill guard)
    }
  }

  float bsum_r = bic[tid] + bhc[tid];
  float rs_r = rs[tid];
  float a_next = Aenc[tid];
  cov_vec[tid] = tanhf(cov_last[tid]);   // cov_vec position-0 entry
  if (t > 0) h_carry[tid] = h_dec[tid];  // commit carry
  __syncthreads();

  for (int s=0;s<CS;s++){
    if (s > 0){
      i32x4 acc0={0,0,0,0}, acc1={0,0,0,0}, acc2={0,0,0,0}, acc3={0,0,0,0};
      #pragma unroll
      for (int kb=0;kb<8;kb++){
        i32x4 bfr = *(const i32x4*)&h8w[kb*16 + (l>>4)*4];   // broadcast B frag
        acc0 = __builtin_amdgcn_mfma_i32_16x16x64_i8(af[0][kb], bfr, acc0, 0,0,0);
        acc1 = __builtin_amdgcn_mfma_i32_16x16x64_i8(af[1][kb], bfr, acc1, 0,0,0);
        acc2 = __builtin_amdgcn_mfma_i32_16x16x64_i8(af[2][kb], bfr, acc2, 0,0,0);
        acc3 = __builtin_amdgcn_mfma_i32_16x16x64_i8(af[3][kb], bfr, acc3, 0,0,0);
      }
      if ((l & 15) == 0){      // col-0 lanes hold D rows (l>>4)*4 + r4
        int rq = l >> 4;
        *(i32x4*)&part_l[(4*w+0)*16 + rq*4] = acc0;
        *(i32x4*)&part_l[(4*w+1)*16 + rq*4] = acc1;
        *(i32x4*)&part_l[(4*w+2)*16 + rq*4] = acc2;
        *(i32x4*)&part_l[(4*w+3)*16 + rq*4] = acc3;
      }
    }
    COVBAR();   // D ints in LDS (lgkm-only)
    {
      float T = (s > 0) ? (float)(int)part_l[tid] * rs_r : 0.f;
      float a_cur = a_next;
      if (s < CS-1) a_next = Aenc[(s+1)*CH + tid];
      float h = tanhf(T + al_l[s]*(a_cur + bacc_r) + bsum_r);
      if (s < CS-1){
        int q = (int)rintf(h * 127.f);
        u32 bq = (u32)(q & 255);
        u32 p01 = bq | (__shfl_xor(bq,1) << 8);
        u32 p = p01 | (__shfl_xor(p01,2) << 16);
        if ((tid & 3) == 0) h8w[tid >> 2] = p;
        cov_vec[(s+1)*CH + tid] = tanhf(h);   // fire-and-forget
      } else {
        cov_last[tid] = h;
      }
    }
    COVBAR();   // h8w ready for next position
  }
}

// ---------------- host ----------------
extern "C" void kernel_launch(void* const* d_in, const int* in_sizes, int n_in,
                              void* d_out, int out_size, void* d_ws, size_t ws_size,
                              hipStream_t stream){
  (void)in_sizes; (void)n_in; (void)out_size;
  const int*   iseq = (const int*)d_in[0];
  const int*   oseq = (const int*)d_in[1];
  const float* ee   = (const float*)d_in[2];
  const float* de   = (const float*)d_in[3];
  const float* Wih_f=(const float*)d_in[4];  const float* Whh_f=(const float*)d_in[5];
  const float* bih_f=(const float*)d_in[6];  const float* bhh_f=(const float*)d_in[7];
  const float* Wih_b=(const float*)d_in[8];  const float* Whh_b=(const float*)d_in[9];
  const float* bih_b=(const float*)d_in[10]; const float* bhh_b=(const float*)d_in[11];
  const float* Wih_d=(const float*)d_in[12]; const float* Whh_d=(const float*)d_in[13];
  const float* bih_d=(const float*)d_in[14]; const float* bhh_d=(const float*)d_in[15];
  const float* Wih_c=(const float*)d_in[16]; const float* Whh_c=(const float*)d_in[17];
  const float* bih_c=(const float*)d_in[18]; const float* bhh_c=(const float*)d_in[19];
  const float* va   =(const float*)d_in[20]; const float* wa   =(const float*)d_in[21];
  const float* ua   =(const float*)d_in[22]; const float* vc   =(const float*)d_in[23];
  const float* lin_W=(const float*)d_in[24]; const float* lin_b=(const float*)d_in[25];
  float* out = (float*)d_out;
  char* ws = (char*)d_ws;

  size_t off = 0;
  auto A = [&](size_t bytes){ size_t r = off; off = (off + bytes + 255) & ~(size_t)255; return r; };
  size_t o_w8m   = A((size_t)CH*128*4);      // i8 MFMA A-frags (256 KB)
  size_t o_rs    = A((size_t)CH*4);
  size_t o_wicP  = A((size_t)256*512*4);     // packed-transposed fp16 Wih_c slice
  size_t o_xenc = A((size_t)CS*CE*4), o_xdec = A((size_t)CT*CE*4);
  size_t o_gf   = A((size_t)CS*CH3*4), o_gb  = A((size_t)CS*CH3*4);
  size_t o_of   = A((size_t)CS*CH*4),  o_ob  = A((size_t)CS*CH*4);
  size_t o_uae  = A((size_t)CS*CH*4),  o_Ae  = A((size_t)CS*CH*4);
  size_t o_e    = A(CS*4), o_al = A(CS*4), o_ctx = A(CH2*4);
  size_t o_hc   = A(CH*4), o_hn = A(CH*4), o_cl = A(CH*4);
  size_t o_wah  = A(CH*4);
  size_t o_cv   = A((size_t)CS*CH*4);
  size_t o_lwb  = A((size_t)CV*CH3*2);
  bool use16 = (off <= ws_size);

  uint4* w8m = (uint4*)(ws+o_w8m);    float* rs = (float*)(ws+o_rs);
  u32* wic16P = (u32*)(ws+o_wicP);
  float* x_enc = (float*)(ws+o_xenc); float* x_dec = (float*)(ws+o_xdec);
  float* gf = (float*)(ws+o_gf);      float* gb = (float*)(ws+o_gb);
  float* outf = (float*)(ws+o_of);    float* outb = (float*)(ws+o_ob);
  float* ua_enc = (float*)(ws+o_uae); float* Aenc = (float*)(ws+o_Ae);
  float* e = (float*)(ws+o_e);        float* alpha = (float*)(ws+o_al);
  float* ctx = (float*)(ws+o_ctx);
  float* h_carry = (float*)(ws+o_hc); float* h_cur = (float*)(ws+o_hn);
  float* cov_last = (float*)(ws+o_cl);
  float* wah = (float*)(ws+o_wah);
  float* cov_vec = (float*)(ws+o_cv);
  u16* lwb = (u16*)(ws+o_lwb);

  k_init<<<1,256,0,stream>>>(cov_last);
  k_embed<<<CS,256,0,stream>>>(iseq, oseq, ee, de, x_enc, x_dec);
  k_gi<<<(2*CS*CH3)/256,256,0,stream>>>(Wih_f,bih_f,Wih_b,bih_b,x_enc,gf,gb);
  for (int s=0;s<CS;s++)
    k_enc_step<<<16,256,0,stream>>>(s, Whh_f,bhh_f,Whh_b,bhh_b, gf,gb, outf,outb);
  k_prep2<<<(2*CS*CH+CH)/256,256,0,stream>>>(ua, Wih_c, outf, outb, ua_enc, Aenc, h_carry);
  k_cvt_cov<<<(256*512)/256,256,0,stream>>>(Wih_c, wic16P);
  k_quant<<<CH,64,0,stream>>>(Whh_c, w8m, rs);
  if (use16)
    k_cvt<<<2048,256,0,stream>>>(lin_W, lwb, CV*CH3);
  k_wah<<<8,256,0,stream>>>(wa, h_carry, wah);   // initial wah = wa @ h_enc

  for (int t=0;t<CT;t++){
    k_attn<<<CS,256,0,stream>>>(t, vc, va, ua_enc, cov_vec, wah, e);
    k_soft<<<1,128,0,stream>>>(e, outf, outb, alpha, ctx);
    k_gru<<<64,256,0,stream>>>(t, Wih_d,bih_d,Whh_d,bhh_d, ctx, x_dec, h_carry, h_cur);
    if (use16)
      k_tail<1><<<103,512,0,stream>>>(t, (const void*)lwb, lin_b, h_cur, ctx, out, wa, wah,
                                      w8m, rs, wic16P, bih_c, bhh_c, Aenc, alpha,
                                      cov_vec, cov_last, h_carry);
    else
      k_tail<0><<<103,512,0,stream>>>(t, (const void*)lin_W, lin_b, h_cur, ctx, out, wa, wah,
                                      w8m, rs, wic16P, bih_c, bhh_c, Aenc, alpha,
                                      cov_vec, cov_last, h_carry);
  }
}